// Round 1
// baseline (1817.381 us; speedup 1.0000x reference)
//
#include <hip/hip_runtime.h>
#include <cstdint>

#define NB 2
#define NPER 65536
#define NPTS (NB*NPER)
#define CDIM 128
#define SV 64
#define VOX (SV*SV*SV)
#define WCOLS 1217
#define WSTRIDE 1232   // padded row stride (multiple of 16 floats -> 64B-aligned rows)

// Padded Wh3 lives in a static device buffer (rewritten every call; deterministic).
__device__ __align__(16) float g_Wh3p[32*WSTRIDE];

__global__ __launch_bounds__(256) void pad_wh3_kernel(const float* __restrict__ Wh3){
    int idx = blockIdx.x*256 + threadIdx.x;
    if (idx < 32*WCOLS){
        int k = idx / WCOLS;
        int c = idx - k*WCOLS;
        g_Wh3p[k*WSTRIDE + c] = Wh3[idx];
    }
}

// c_plane [B][C=128][VOX] -> ct [B][VOX][C=128]
__global__ __launch_bounds__(256) void transpose_kernel(const float* __restrict__ in,
                                                        float* __restrict__ out){
    __shared__ float tile[128][33];
    const int blk = blockIdx.x;        // NB * (VOX/32) blocks
    const int b  = blk >> 13;          // VOX/32 = 8192
    const int v0 = (blk & 8191) << 5;  // *32
    const int tx = threadIdx.x & 31;
    const int ty = threadIdx.x >> 5;   // 0..7
    const float* ip = in + (size_t)b*128*VOX + v0;
    #pragma unroll
    for (int cc = 0; cc < 16; cc++){
        int c = cc*8 + ty;
        tile[c][tx] = ip[(size_t)c*VOX + tx];
    }
    __syncthreads();
    const int cx = threadIdx.x & 127;
    const int vy = threadIdx.x >> 7;   // 0..1
    float* op = out + ((size_t)b*VOX + v0)*128;
    #pragma unroll
    for (int vv = 0; vv < 16; vv++){
        int v = vv*2 + vy;
        op[(size_t)v*128 + cx] = tile[cx][v];
    }
}

// wave-per-point trilinear sample from channel-last ct; lane handles 2 channels
__global__ __launch_bounds__(256) void sample_kernel(const float* __restrict__ pcl_mem,
                                                     const float* __restrict__ ct,
                                                     float* __restrict__ feats){
    const int tid  = threadIdx.x;
    const int lane = tid & 63;
    const int p    = blockIdx.x*4 + (tid >> 6);
    const int b    = p >> 16;

    float v0 = pcl_mem[3*p+0], v1 = pcl_mem[3*p+1], v2 = pcl_mem[3*p+2];
    auto src = [](float v){
        float g = 2.0f*v/63.0f - 1.0f;
        g = fminf(fmaxf(g, -2.0f), 2.0f);
        float t = (g + 1.0f)*0.5f*63.0f;
        return fminf(fmaxf(t, 0.0f), 63.0f);
    };
    float ix = src(v0), iy = src(v1), iz = src(v2);
    float fx = floorf(ix), fy = floorf(iy), fz = floorf(iz);
    float wx = ix-fx, wy = iy-fy, wz = iz-fz;
    int x0 = min(max((int)fx,0),63); int x1 = min(x0+1,63);
    int y0 = min(max((int)fy,0),63); int y1 = min(y0+1,63);
    int z0 = min(max((int)fz,0),63); int z1 = min(z0+1,63);
    float wx0 = 1.f-wx, wy0 = 1.f-wy, wz0 = 1.f-wz;

    const float2* base = (const float2*)ct + (size_t)b*VOX*64 + lane;
    float ax = 0.f, ay = 0.f;
#define CORNER(zz,yy,xx,wgt) { \
        float2 cv = base[(size_t)(((zz)*64+(yy))*64+(xx))*64]; \
        float w_ = (wgt); \
        ax = fmaf(w_, cv.x, ax); ay = fmaf(w_, cv.y, ay); }
    CORNER(z0,y0,x0, wz0*wy0*wx0);
    CORNER(z0,y0,x1, wz0*wy0*wx );
    CORNER(z0,y1,x0, wz0*wy *wx0);
    CORNER(z0,y1,x1, wz0*wy *wx );
    CORNER(z1,y0,x0, wz *wy0*wx0);
    CORNER(z1,y0,x1, wz *wy0*wx );
    CORNER(z1,y1,x0, wz *wy *wx0);
    CORNER(z1,y1,x1, wz *wy *wx );
#undef CORNER
    ((float2*)(feats + (size_t)p*CDIM))[lane] = make_float2(ax, ay);
}

// fallback (ws too small): thread per (point, channel), original layout
__global__ __launch_bounds__(256) void sample_slow_kernel(const float* __restrict__ pcl_mem,
                                                          const float* __restrict__ cpl,
                                                          float* __restrict__ feats){
    int gid = blockIdx.x*256 + threadIdx.x;   // p*128 + c
    int p = gid >> 7; int c = gid & 127;
    int b = p >> 16;
    float v0 = pcl_mem[3*p+0], v1 = pcl_mem[3*p+1], v2 = pcl_mem[3*p+2];
    auto src = [](float v){
        float g = 2.0f*v/63.0f - 1.0f;
        g = fminf(fmaxf(g, -2.0f), 2.0f);
        float t = (g + 1.0f)*0.5f*63.0f;
        return fminf(fmaxf(t, 0.0f), 63.0f);
    };
    float ix = src(v0), iy = src(v1), iz = src(v2);
    float fx = floorf(ix), fy = floorf(iy), fz = floorf(iz);
    float wx = ix-fx, wy = iy-fy, wz = iz-fz;
    int x0 = min(max((int)fx,0),63); int x1 = min(x0+1,63);
    int y0 = min(max((int)fy,0),63); int y1 = min(y0+1,63);
    int z0 = min(max((int)fz,0),63); int z1 = min(z0+1,63);
    float wx0 = 1.f-wx, wy0 = 1.f-wy, wz0 = 1.f-wz;
    const float* base = cpl + ((size_t)(b*128 + c))*VOX;
    float acc = 0.f;
    acc = fmaf(wz0*wy0*wx0, base[(z0*64+y0)*64+x0], acc);
    acc = fmaf(wz0*wy0*wx , base[(z0*64+y0)*64+x1], acc);
    acc = fmaf(wz0*wy *wx0, base[(z0*64+y1)*64+x0], acc);
    acc = fmaf(wz0*wy *wx , base[(z0*64+y1)*64+x1], acc);
    acc = fmaf(wz *wy0*wx0, base[(z1*64+y0)*64+x0], acc);
    acc = fmaf(wz *wy0*wx , base[(z1*64+y0)*64+x1], acc);
    acc = fmaf(wz *wy *wx0, base[(z1*64+y1)*64+x0], acc);
    acc = fmaf(wz *wy *wx , base[(z1*64+y1)*64+x1], acc);
    feats[gid] = acc;
}

__device__ __forceinline__ void fma4(float (&acc)[32], int jv, float s, float4 w){
    acc[4*jv+0] = fmaf(s, w.x, acc[4*jv+0]);
    acc[4*jv+1] = fmaf(s, w.y, acc[4*jv+1]);
    acc[4*jv+2] = fmaf(s, w.z, acc[4*jv+2]);
    acc[4*jv+3] = fmaf(s, w.w, acc[4*jv+3]);
}

// thread-per-point fused MLP + hypernetwork (hw never materialized).
// Single 32 KiB LDS array (occupancy lever: 5 blocks/CU instead of 2).
// h2a lives purely in registers; every loop that consumes h2a[k] has k
// unrolled (static index). Only a1 (runtime-i in the main contraction)
// and the h1a/leaky(o2) bounces use LDS. All accumulation orders are
// bit-identical to the previous version.
__global__ __launch_bounds__(256, 5) void mlp_kernel(
        const float* __restrict__ pcl_mem,
        const float* __restrict__ Wh1, const float* __restrict__ bh1,
        const float* __restrict__ Wh2, const float* __restrict__ bh2,
        const float* __restrict__ bh3,
        const float* __restrict__ feats,
        float* __restrict__ outp)
{
    __shared__ float lds_a[32][256];   // h1a, later a1, later leaky(o2); own column only
    const int tid = threadIdx.x;
    const int p   = blockIdx.x*256 + tid;

    float xv0, xv1, xv2;
    {
        float v0 = pcl_mem[3*p+0], v1 = pcl_mem[3*p+1], v2 = pcl_mem[3*p+2];
        xv0 = v0 - truncf(v0) - 0.5f;
        xv1 = v1 - truncf(v1) - 0.5f;
        xv2 = v2 - truncf(v2) - 0.5f;
    }

    const float4* f4  = (const float4*)(feats + (size_t)p*CDIM);
    const float4* W1q = (const float4*)Wh1;
    const float4* W2q = (const float4*)Wh2;
    const float4* W3q = (const float4*)g_Wh3p;
    const float4* b1q = (const float4*)bh1;
    const float4* b2q = (const float4*)bh2;
    const float4* b3q = (const float4*)bh3;
    const int RS = WSTRIDE/4;   // 308 float4 per Wh3p row

    // ---- h1 = leaky(feats @ Wh1 + bh1) ----
    float h1[32];
    #pragma unroll
    for (int jv=0;jv<8;jv++){ float4 bv=b1q[jv]; h1[4*jv]=bv.x; h1[4*jv+1]=bv.y; h1[4*jv+2]=bv.z; h1[4*jv+3]=bv.w; }
    for (int c4=0;c4<32;c4++){
        float4 f = f4[c4];
        float fs[4] = {f.x, f.y, f.z, f.w};
        #pragma unroll
        for (int cc=0;cc<4;cc++){
            #pragma unroll
            for (int jv=0;jv<8;jv++)
                fma4(h1, jv, fs[cc], W1q[(c4*4+cc)*8 + jv]);
        }
    }
    #pragma unroll
    for (int j=0;j<32;j++){ float a=h1[j]; lds_a[j][tid] = fmaxf(a, 0.01f*a); }

    // ---- h2 = leaky(h1a @ Wh2 + bh2) ---- (h2a stays in registers only)
    float h2[32];
    #pragma unroll
    for (int kv=0;kv<8;kv++){ float4 bv=b2q[kv]; h2[4*kv]=bv.x; h2[4*kv+1]=bv.y; h2[4*kv+2]=bv.z; h2[4*kv+3]=bv.w; }
    for (int j=0;j<32;j++){
        float aj = lds_a[j][tid];
        #pragma unroll
        for (int kv=0;kv<8;kv++) fma4(h2, kv, aj, W2q[j*8+kv]);
    }
    float h2a[32];
    #pragma unroll
    for (int k=0;k<32;k++){ float a=h2[k]; h2a[k] = fmaxf(a, 0.01f*a); }

    // ---- o1[j] = x . W1'[:, j] + b1'[j], fused from hw cols 0..127.
    // Chunked: 4 chunks of 8 columns; k unrolled (h2a static). Per-element
    // accumulation order identical to the previous full-width version.
    #pragma unroll 1
    for (int jc=0;jc<4;jc++){
        float acc[8];
        #pragma unroll
        for (int q=0;q<2;q++){
            float4 ba=b3q[jc*2+q], bb=b3q[8+jc*2+q], bc=b3q[16+jc*2+q], bd=b3q[24+jc*2+q];
            acc[4*q+0] = fmaf(xv0,ba.x, fmaf(xv1,bb.x, fmaf(xv2,bc.x, bd.x)));
            acc[4*q+1] = fmaf(xv0,ba.y, fmaf(xv1,bb.y, fmaf(xv2,bc.y, bd.y)));
            acc[4*q+2] = fmaf(xv0,ba.z, fmaf(xv1,bb.z, fmaf(xv2,bc.z, bd.z)));
            acc[4*q+3] = fmaf(xv0,ba.w, fmaf(xv1,bb.w, fmaf(xv2,bc.w, bd.w)));
        }
        #pragma unroll
        for (int k=0;k<32;k++){
            const float4* row = W3q + k*RS + jc*2;
            float hk = h2a[k];
            #pragma unroll
            for (int q=0;q<2;q++){
                float4 wa=row[q], wb=row[8+q], wc=row[16+q], wd=row[24+q];
                acc[4*q+0] = fmaf(hk, fmaf(xv0,wa.x, fmaf(xv1,wb.x, fmaf(xv2,wc.x, wd.x))), acc[4*q+0]);
                acc[4*q+1] = fmaf(hk, fmaf(xv0,wa.y, fmaf(xv1,wb.y, fmaf(xv2,wc.y, wd.y))), acc[4*q+1]);
                acc[4*q+2] = fmaf(hk, fmaf(xv0,wa.z, fmaf(xv1,wb.z, fmaf(xv2,wc.z, wd.z))), acc[4*q+2]);
                acc[4*q+3] = fmaf(hk, fmaf(xv0,wa.w, fmaf(xv1,wb.w, fmaf(xv2,wc.w, wd.w))), acc[4*q+3]);
            }
        }
        #pragma unroll
        for (int r=0;r<8;r++){ float a=acc[r]; lds_a[jc*8+r][tid] = fmaxf(a, 0.01f*a); }  // a1 chunk
    }

    // ---- o2 init = b2' + h2a . W3[:,1152..1183]  (hw cols 1152..1183), k unrolled ----
    float o2[32];
    #pragma unroll
    for (int jv=0;jv<8;jv++){ float4 bv=b3q[288+jv]; o2[4*jv]=bv.x; o2[4*jv+1]=bv.y; o2[4*jv+2]=bv.z; o2[4*jv+3]=bv.w; }
    #pragma unroll
    for (int k=0;k<32;k++){
        const float4* row = W3q + k*RS + 288;
        float hk = h2a[k];
        #pragma unroll
        for (int jv=0;jv<8;jv++) fma4(o2, jv, hk, row[jv]);
    }

    // ---- main contraction: o2[j] += sum_i a1[i] * (bh3 + h2.Wh3)[128+i*32+j] ----
    #pragma unroll 1
    for (int i=0;i<32;i++){
        float ai = lds_a[i][tid];
        float w2[32];
        #pragma unroll
        for (int jv=0;jv<8;jv++){ float4 bv=b3q[32+i*8+jv]; w2[4*jv]=bv.x; w2[4*jv+1]=bv.y; w2[4*jv+2]=bv.z; w2[4*jv+3]=bv.w; }
        #pragma unroll
        for (int k=0;k<32;k++){
            const float4* row = W3q + k*RS + 32 + i*8;
            #pragma unroll
            for (int jv=0;jv<8;jv++) fma4(w2, jv, h2a[k], row[jv]);
        }
        #pragma unroll
        for (int j=0;j<32;j++) o2[j] = fmaf(ai, w2[j], o2[j]);
    }

    // stash a2 = leaky(o2) in LDS (a1 is dead) for chunked final read-back
    #pragma unroll
    for (int j=0;j<32;j++){ float a=o2[j]; lds_a[j][tid] = fmaxf(a, 0.01f*a); }

    // ---- final: o3 = a2 . W3' + b3'  (hw cols 1184..1216) ----
    float o3 = bh3[1216];
    #pragma unroll
    for (int k=0;k<32;k++) o3 = fmaf(h2a[k], g_Wh3p[k*WSTRIDE + 1216], o3);
    #pragma unroll 1
    for (int jc=0;jc<4;jc++){
        float w3c[8];
        #pragma unroll
        for (int q=0;q<2;q++){
            float4 bv=b3q[296+jc*2+q];
            w3c[4*q]=bv.x; w3c[4*q+1]=bv.y; w3c[4*q+2]=bv.z; w3c[4*q+3]=bv.w;
        }
        #pragma unroll
        for (int k=0;k<32;k++){
            const float4* row = W3q + k*RS + 296 + jc*2;
            float hk = h2a[k];
            #pragma unroll
            for (int q=0;q<2;q++){
                float4 w=row[q];
                w3c[4*q+0] = fmaf(hk, w.x, w3c[4*q+0]);
                w3c[4*q+1] = fmaf(hk, w.y, w3c[4*q+1]);
                w3c[4*q+2] = fmaf(hk, w.z, w3c[4*q+2]);
                w3c[4*q+3] = fmaf(hk, w.w, w3c[4*q+3]);
            }
        }
        #pragma unroll
        for (int r=0;r<8;r++) o3 = fmaf(lds_a[jc*8+r][tid], w3c[r], o3);
    }

    outp[p] = o3;
}

extern "C" void kernel_launch(void* const* d_in, const int* in_sizes, int n_in,
                              void* d_out, int out_size, void* d_ws, size_t ws_size,
                              hipStream_t stream)
{
    const float* pcl_mem = (const float*)d_in[1];
    const float* c_plane = (const float*)d_in[2];
    const float* Wh1     = (const float*)d_in[3];
    const float* bh1     = (const float*)d_in[4];
    const float* Wh2     = (const float*)d_in[5];
    const float* bh2     = (const float*)d_in[6];
    const float* Wh3     = (const float*)d_in[7];
    const float* bh3     = (const float*)d_in[8];
    float* outp  = (float*)d_out;
    float* feats = outp + NPTS;

    pad_wh3_kernel<<<(32*WCOLS+255)/256, 256, 0, stream>>>(Wh3);

    const size_t ct_bytes = (size_t)NB*VOX*CDIM*sizeof(float);   // 256 MiB
    if (ws_size >= ct_bytes) {
        float* ct = (float*)d_ws;
        transpose_kernel<<<NB*(VOX/32), 256, 0, stream>>>(c_plane, ct);
        sample_kernel<<<NPTS/4, 256, 0, stream>>>(pcl_mem, ct, feats);
    } else {
        sample_slow_kernel<<<(NPTS*CDIM)/256, 256, 0, stream>>>(pcl_mem, c_plane, feats);
    }

    mlp_kernel<<<NPTS/256, 256, 0, stream>>>(pcl_mem, Wh1, bh1, Wh2, bh2, bh3, feats, outp);
}

// Round 2
// 1208.498 us; speedup vs baseline: 1.5038x; 1.5038x over previous
//
#include <hip/hip_runtime.h>
#include <cstdint>

#define NB 2
#define NPER 65536
#define NPTS (NB*NPER)
#define CDIM 128
#define SV 64
#define VOX (SV*SV*SV)
#define WCOLS 1217
#define WSTRIDE 1232   // padded row stride (multiple of 16 floats -> 64B-aligned rows)

// Padded Wh3 lives in a static device buffer (rewritten every call; deterministic).
__device__ __align__(16) float g_Wh3p[32*WSTRIDE];

__global__ __launch_bounds__(256) void pad_wh3_kernel(const float* __restrict__ Wh3){
    int idx = blockIdx.x*256 + threadIdx.x;
    if (idx < 32*WCOLS){
        int k = idx / WCOLS;
        int c = idx - k*WCOLS;
        g_Wh3p[k*WSTRIDE + c] = Wh3[idx];
    }
}

// c_plane [B][C=128][VOX] -> ct [B][VOX][C=128]
__global__ __launch_bounds__(256) void transpose_kernel(const float* __restrict__ in,
                                                        float* __restrict__ out){
    __shared__ float tile[128][33];
    const int blk = blockIdx.x;        // NB * (VOX/32) blocks
    const int b  = blk >> 13;          // VOX/32 = 8192
    const int v0 = (blk & 8191) << 5;  // *32
    const int tx = threadIdx.x & 31;
    const int ty = threadIdx.x >> 5;   // 0..7
    const float* ip = in + (size_t)b*128*VOX + v0;
    #pragma unroll
    for (int cc = 0; cc < 16; cc++){
        int c = cc*8 + ty;
        tile[c][tx] = ip[(size_t)c*VOX + tx];
    }
    __syncthreads();
    const int cx = threadIdx.x & 127;
    const int vy = threadIdx.x >> 7;   // 0..1
    float* op = out + ((size_t)b*VOX + v0)*128;
    #pragma unroll
    for (int vv = 0; vv < 16; vv++){
        int v = vv*2 + vy;
        op[(size_t)v*128 + cx] = tile[cx][v];
    }
}

// wave-per-point trilinear sample from channel-last ct; lane handles 2 channels
__global__ __launch_bounds__(256) void sample_kernel(const float* __restrict__ pcl_mem,
                                                     const float* __restrict__ ct,
                                                     float* __restrict__ feats){
    const int tid  = threadIdx.x;
    const int lane = tid & 63;
    const int p    = blockIdx.x*4 + (tid >> 6);
    const int b    = p >> 16;

    float v0 = pcl_mem[3*p+0], v1 = pcl_mem[3*p+1], v2 = pcl_mem[3*p+2];
    auto src = [](float v){
        float g = 2.0f*v/63.0f - 1.0f;
        g = fminf(fmaxf(g, -2.0f), 2.0f);
        float t = (g + 1.0f)*0.5f*63.0f;
        return fminf(fmaxf(t, 0.0f), 63.0f);
    };
    float ix = src(v0), iy = src(v1), iz = src(v2);
    float fx = floorf(ix), fy = floorf(iy), fz = floorf(iz);
    float wx = ix-fx, wy = iy-fy, wz = iz-fz;
    int x0 = min(max((int)fx,0),63); int x1 = min(x0+1,63);
    int y0 = min(max((int)fy,0),63); int y1 = min(y0+1,63);
    int z0 = min(max((int)fz,0),63); int z1 = min(z0+1,63);
    float wx0 = 1.f-wx, wy0 = 1.f-wy, wz0 = 1.f-wz;

    const float2* base = (const float2*)ct + (size_t)b*VOX*64 + lane;
    float ax = 0.f, ay = 0.f;
#define CORNER(zz,yy,xx,wgt) { \
        float2 cv = base[(size_t)(((zz)*64+(yy))*64+(xx))*64]; \
        float w_ = (wgt); \
        ax = fmaf(w_, cv.x, ax); ay = fmaf(w_, cv.y, ay); }
    CORNER(z0,y0,x0, wz0*wy0*wx0);
    CORNER(z0,y0,x1, wz0*wy0*wx );
    CORNER(z0,y1,x0, wz0*wy *wx0);
    CORNER(z0,y1,x1, wz0*wy *wx );
    CORNER(z1,y0,x0, wz *wy0*wx0);
    CORNER(z1,y0,x1, wz *wy0*wx );
    CORNER(z1,y1,x0, wz *wy *wx0);
    CORNER(z1,y1,x1, wz *wy *wx );
#undef CORNER
    ((float2*)(feats + (size_t)p*CDIM))[lane] = make_float2(ax, ay);
}

// fallback (ws too small): thread per (point, channel), original layout
__global__ __launch_bounds__(256) void sample_slow_kernel(const float* __restrict__ pcl_mem,
                                                          const float* __restrict__ cpl,
                                                          float* __restrict__ feats){
    int gid = blockIdx.x*256 + threadIdx.x;   // p*128 + c
    int p = gid >> 7; int c = gid & 127;
    int b = p >> 16;
    float v0 = pcl_mem[3*p+0], v1 = pcl_mem[3*p+1], v2 = pcl_mem[3*p+2];
    auto src = [](float v){
        float g = 2.0f*v/63.0f - 1.0f;
        g = fminf(fmaxf(g, -2.0f), 2.0f);
        float t = (g + 1.0f)*0.5f*63.0f;
        return fminf(fmaxf(t, 0.0f), 63.0f);
    };
    float ix = src(v0), iy = src(v1), iz = src(v2);
    float fx = floorf(ix), fy = floorf(iy), fz = floorf(iz);
    float wx = ix-fx, wy = iy-fy, wz = iz-fz;
    int x0 = min(max((int)fx,0),63); int x1 = min(x0+1,63);
    int y0 = min(max((int)fy,0),63); int y1 = min(y0+1,63);
    int z0 = min(max((int)fz,0),63); int z1 = min(z0+1,63);
    float wx0 = 1.f-wx, wy0 = 1.f-wy, wz0 = 1.f-wz;
    const float* base = cpl + ((size_t)(b*128 + c))*VOX;
    float acc = 0.f;
    acc = fmaf(wz0*wy0*wx0, base[(z0*64+y0)*64+x0], acc);
    acc = fmaf(wz0*wy0*wx , base[(z0*64+y0)*64+x1], acc);
    acc = fmaf(wz0*wy *wx0, base[(z0*64+y1)*64+x0], acc);
    acc = fmaf(wz0*wy *wx , base[(z0*64+y1)*64+x1], acc);
    acc = fmaf(wz *wy0*wx0, base[(z1*64+y0)*64+x0], acc);
    acc = fmaf(wz *wy0*wx , base[(z1*64+y0)*64+x1], acc);
    acc = fmaf(wz *wy *wx0, base[(z1*64+y1)*64+x0], acc);
    acc = fmaf(wz *wy *wx , base[(z1*64+y1)*64+x1], acc);
    feats[gid] = acc;
}

// ---------------------------------------------------------------------------
// Fused MLP + hypernetwork, 2 THREADS PER POINT.
//   block = 256 threads = 128 points; grid = NPTS/128 = 1024 blocks
//   -> 4 blocks/CU resident (vs 2 before), 4 waves/SIMD of latency hiding.
// Thread (pl, half) owns output columns [half*16, half*16+16) of every
// 32-wide stage (h1, h2, o1/a1, o2). Cross-half values are exchanged via a
// single 16 KB LDS buffer xbuf[32][128] (lane-stride-1 -> conflict-free).
// Per-element FMA accumulation order matches the 395us round-0 kernel
// (only the final o3 sum is reassociated: base + part0 + part1).
// ---------------------------------------------------------------------------
__global__ __launch_bounds__(256) void mlp_kernel(
        const float* __restrict__ pcl_mem,
        const float* __restrict__ Wh1, const float* __restrict__ bh1,
        const float* __restrict__ Wh2, const float* __restrict__ bh2,
        const float* __restrict__ bh3,
        const float* __restrict__ feats,
        float* __restrict__ outp)
{
    __shared__ float xbuf[32][128];     // 16 KB: h1a -> h2a -> a1 -> o3 partials
    const int tid  = threadIdx.x;
    const int pl   = tid & 127;         // point within block
    const int half = tid >> 7;          // 0 or 1: which 16-column half
    const int p    = blockIdx.x*128 + pl;
    const int jq   = half*4;            // float4-group base of my half

    float xv0, xv1, xv2;
    {
        float v0 = pcl_mem[3*p+0], v1 = pcl_mem[3*p+1], v2 = pcl_mem[3*p+2];
        xv0 = v0 - truncf(v0) - 0.5f;
        xv1 = v1 - truncf(v1) - 0.5f;
        xv2 = v2 - truncf(v2) - 0.5f;
    }

    const float4* f4  = (const float4*)(feats + (size_t)p*CDIM);
    const float4* W1q = (const float4*)Wh1;
    const float4* W2q = (const float4*)Wh2;
    const float4* W3q = (const float4*)g_Wh3p;
    const float4* b1q = (const float4*)bh1;
    const float4* b2q = (const float4*)bh2;
    const float4* b3q = (const float4*)bh3;
    const int RS = WSTRIDE/4;   // 308 float4 per Wh3p row

    // ---- h1 half: 16 cols of leaky(feats @ Wh1 + bh1) ----
    float hh[16];
    #pragma unroll
    for (int q=0;q<4;q++){ float4 bv=b1q[jq+q]; hh[4*q]=bv.x; hh[4*q+1]=bv.y; hh[4*q+2]=bv.z; hh[4*q+3]=bv.w; }
    for (int c4=0;c4<32;c4++){
        float4 f = f4[c4];
        float fs[4] = {f.x, f.y, f.z, f.w};
        #pragma unroll
        for (int cc=0;cc<4;cc++){
            #pragma unroll
            for (int q=0;q<4;q++){
                float4 w = W1q[(c4*4+cc)*8 + jq + q];
                hh[4*q+0] = fmaf(fs[cc], w.x, hh[4*q+0]);
                hh[4*q+1] = fmaf(fs[cc], w.y, hh[4*q+1]);
                hh[4*q+2] = fmaf(fs[cc], w.z, hh[4*q+2]);
                hh[4*q+3] = fmaf(fs[cc], w.w, hh[4*q+3]);
            }
        }
    }
    #pragma unroll
    for (int r=0;r<16;r++){ float a=hh[r]; xbuf[half*16+r][pl] = fmaxf(a, 0.01f*a); }
    __syncthreads();

    // ---- h2 half: 16 cols of h1a @ Wh2 + bh2 ----
    float h2[16];
    #pragma unroll
    for (int q=0;q<4;q++){ float4 bv=b2q[jq+q]; h2[4*q]=bv.x; h2[4*q+1]=bv.y; h2[4*q+2]=bv.z; h2[4*q+3]=bv.w; }
    #pragma unroll
    for (int i=0;i<32;i++){
        float ai = xbuf[i][pl];
        #pragma unroll
        for (int q=0;q<4;q++){
            float4 w = W2q[i*8 + jq + q];
            h2[4*q+0] = fmaf(ai, w.x, h2[4*q+0]);
            h2[4*q+1] = fmaf(ai, w.y, h2[4*q+1]);
            h2[4*q+2] = fmaf(ai, w.z, h2[4*q+2]);
            h2[4*q+3] = fmaf(ai, w.w, h2[4*q+3]);
        }
    }
    __syncthreads();   // all h1a reads done -> safe to overwrite
    #pragma unroll
    for (int r=0;r<16;r++){ float a=h2[r]; xbuf[half*16+r][pl] = fmaxf(a, 0.01f*a); }
    __syncthreads();
    float h2a[32];     // full h2a in registers (static-indexed everywhere below)
    #pragma unroll
    for (int k=0;k<32;k++) h2a[k] = xbuf[k][pl];

    // ---- o1 half: 16 cols of x . W1' + b1' (hw cols 0..127), k unrolled ----
    float acc[16];
    #pragma unroll
    for (int q=0;q<4;q++){
        float4 ba=b3q[jq+q], bb=b3q[8+jq+q], bc=b3q[16+jq+q], bd=b3q[24+jq+q];
        acc[4*q+0] = fmaf(xv0,ba.x, fmaf(xv1,bb.x, fmaf(xv2,bc.x, bd.x)));
        acc[4*q+1] = fmaf(xv0,ba.y, fmaf(xv1,bb.y, fmaf(xv2,bc.y, bd.y)));
        acc[4*q+2] = fmaf(xv0,ba.z, fmaf(xv1,bb.z, fmaf(xv2,bc.z, bd.z)));
        acc[4*q+3] = fmaf(xv0,ba.w, fmaf(xv1,bb.w, fmaf(xv2,bc.w, bd.w)));
    }
    #pragma unroll
    for (int k=0;k<32;k++){
        const float4* row = W3q + (size_t)k*RS;
        float hk = h2a[k];
        #pragma unroll
        for (int q=0;q<4;q++){
            float4 wa=row[jq+q], wb=row[8+jq+q], wc=row[16+jq+q], wd=row[24+jq+q];
            acc[4*q+0] = fmaf(hk, fmaf(xv0,wa.x, fmaf(xv1,wb.x, fmaf(xv2,wc.x, wd.x))), acc[4*q+0]);
            acc[4*q+1] = fmaf(hk, fmaf(xv0,wa.y, fmaf(xv1,wb.y, fmaf(xv2,wc.y, wd.y))), acc[4*q+1]);
            acc[4*q+2] = fmaf(hk, fmaf(xv0,wa.z, fmaf(xv1,wb.z, fmaf(xv2,wc.z, wd.z))), acc[4*q+2]);
            acc[4*q+3] = fmaf(hk, fmaf(xv0,wa.w, fmaf(xv1,wb.w, fmaf(xv2,wc.w, wd.w))), acc[4*q+3]);
        }
    }
    __syncthreads();   // all h2a reads from xbuf done -> safe to overwrite
    #pragma unroll
    for (int r=0;r<16;r++){ float a=acc[r]; xbuf[half*16+r][pl] = fmaxf(a, 0.01f*a); }  // a1
    __syncthreads();

    // ---- o2 init half: b2' + h2a . W3[:,1152..1183], k unrolled ----
    float o2[16];
    #pragma unroll
    for (int q=0;q<4;q++){ float4 bv=b3q[288+jq+q]; o2[4*q]=bv.x; o2[4*q+1]=bv.y; o2[4*q+2]=bv.z; o2[4*q+3]=bv.w; }
    #pragma unroll
    for (int k=0;k<32;k++){
        const float4* row = W3q + (size_t)k*RS + 288;
        float hk = h2a[k];
        #pragma unroll
        for (int q=0;q<4;q++){
            float4 w = row[jq+q];
            o2[4*q+0] = fmaf(hk, w.x, o2[4*q+0]);
            o2[4*q+1] = fmaf(hk, w.y, o2[4*q+1]);
            o2[4*q+2] = fmaf(hk, w.z, o2[4*q+2]);
            o2[4*q+3] = fmaf(hk, w.w, o2[4*q+3]);
        }
    }

    // ---- main contraction: o2[j] += sum_i a1[i] * (bh3 + h2.Wh3)[128+i*32+j] ----
    #pragma unroll 1
    for (int i=0;i<32;i++){
        float ai = xbuf[i][pl];
        float w2[16];
        #pragma unroll
        for (int q=0;q<4;q++){ float4 bv=b3q[32+i*8+jq+q]; w2[4*q]=bv.x; w2[4*q+1]=bv.y; w2[4*q+2]=bv.z; w2[4*q+3]=bv.w; }
        #pragma unroll
        for (int k=0;k<32;k++){
            const float4* row = W3q + (size_t)k*RS + 32 + i*8;
            float hk = h2a[k];
            #pragma unroll
            for (int q=0;q<4;q++){
                float4 w = row[jq+q];
                w2[4*q+0] = fmaf(hk, w.x, w2[4*q+0]);
                w2[4*q+1] = fmaf(hk, w.y, w2[4*q+1]);
                w2[4*q+2] = fmaf(hk, w.z, w2[4*q+2]);
                w2[4*q+3] = fmaf(hk, w.w, w2[4*q+3]);
            }
        }
        #pragma unroll
        for (int r=0;r<16;r++) o2[r] = fmaf(ai, w2[r], o2[r]);
    }

    // ---- final half: w3' cols (hw 1184..1215), partial o3 over my 16 cols ----
    float w3c[16];
    #pragma unroll
    for (int q=0;q<4;q++){ float4 bv=b3q[296+jq+q]; w3c[4*q]=bv.x; w3c[4*q+1]=bv.y; w3c[4*q+2]=bv.z; w3c[4*q+3]=bv.w; }
    #pragma unroll
    for (int k=0;k<32;k++){
        const float4* row = W3q + (size_t)k*RS + 296;
        float hk = h2a[k];
        #pragma unroll
        for (int q=0;q<4;q++){
            float4 w = row[jq+q];
            w3c[4*q+0] = fmaf(hk, w.x, w3c[4*q+0]);
            w3c[4*q+1] = fmaf(hk, w.y, w3c[4*q+1]);
            w3c[4*q+2] = fmaf(hk, w.z, w3c[4*q+2]);
            w3c[4*q+3] = fmaf(hk, w.w, w3c[4*q+3]);
        }
    }
    float part = 0.f;
    #pragma unroll
    for (int r=0;r<16;r++){ float a=o2[r]; a = fmaxf(a, 0.01f*a); part = fmaf(a, w3c[r], part); }

    __syncthreads();   // all a1 reads done -> xbuf reusable for reduction
    xbuf[half][pl] = part;
    __syncthreads();
    if (half == 0){
        float base = bh3[1216];
        #pragma unroll
        for (int k=0;k<32;k++) base = fmaf(h2a[k], g_Wh3p[k*WSTRIDE + 1216], base);
        outp[p] = base + xbuf[0][pl] + xbuf[1][pl];
    }
}

extern "C" void kernel_launch(void* const* d_in, const int* in_sizes, int n_in,
                              void* d_out, int out_size, void* d_ws, size_t ws_size,
                              hipStream_t stream)
{
    const float* pcl_mem = (const float*)d_in[1];
    const float* c_plane = (const float*)d_in[2];
    const float* Wh1     = (const float*)d_in[3];
    const float* bh1     = (const float*)d_in[4];
    const float* Wh2     = (const float*)d_in[5];
    const float* bh2     = (const float*)d_in[6];
    const float* Wh3     = (const float*)d_in[7];
    const float* bh3     = (const float*)d_in[8];
    float* outp  = (float*)d_out;
    float* feats = outp + NPTS;

    pad_wh3_kernel<<<(32*WCOLS+255)/256, 256, 0, stream>>>(Wh3);

    const size_t ct_bytes = (size_t)NB*VOX*CDIM*sizeof(float);   // 256 MiB
    if (ws_size >= ct_bytes) {
        float* ct = (float*)d_ws;
        transpose_kernel<<<NB*(VOX/32), 256, 0, stream>>>(c_plane, ct);
        sample_kernel<<<NPTS/4, 256, 0, stream>>>(pcl_mem, ct, feats);
    } else {
        sample_slow_kernel<<<(NPTS*CDIM)/256, 256, 0, stream>>>(pcl_mem, c_plane, feats);
    }

    mlp_kernel<<<NPTS/128, 256, 0, stream>>>(pcl_mem, Wh1, bh1, Wh2, bh2, bh3, feats, outp);
}

// Round 3
// 1137.933 us; speedup vs baseline: 1.5971x; 1.0620x over previous
//
#include <hip/hip_runtime.h>
#include <cstdint>

#define NB 2
#define NPER 65536
#define NPTS (NB*NPER)
#define CDIM 128
#define SV 64
#define VOX (SV*SV*SV)
#define WCOLS 1217
#define WSTRIDE 1232   // padded row stride (multiple of 16 floats -> 64B-aligned rows)

// Padded Wh3 lives in a static device buffer (rewritten every call; deterministic).
__device__ __align__(16) float g_Wh3p[32*WSTRIDE];

__global__ __launch_bounds__(256) void pad_wh3_kernel(const float* __restrict__ Wh3){
    int idx = blockIdx.x*256 + threadIdx.x;
    if (idx < 32*WCOLS){
        int k = idx / WCOLS;
        int c = idx - k*WCOLS;
        g_Wh3p[k*WSTRIDE + c] = Wh3[idx];
    }
}

// c_plane [B][C=128][VOX] -> ct [B][VOX][C=128]
__global__ __launch_bounds__(256) void transpose_kernel(const float* __restrict__ in,
                                                        float* __restrict__ out){
    __shared__ float tile[128][33];
    const int blk = blockIdx.x;        // NB * (VOX/32) blocks
    const int b  = blk >> 13;          // VOX/32 = 8192
    const int v0 = (blk & 8191) << 5;  // *32
    const int tx = threadIdx.x & 31;
    const int ty = threadIdx.x >> 5;   // 0..7
    const float* ip = in + (size_t)b*128*VOX + v0;
    #pragma unroll
    for (int cc = 0; cc < 16; cc++){
        int c = cc*8 + ty;
        tile[c][tx] = ip[(size_t)c*VOX + tx];
    }
    __syncthreads();
    const int cx = threadIdx.x & 127;
    const int vy = threadIdx.x >> 7;   // 0..1
    float* op = out + ((size_t)b*VOX + v0)*128;
    #pragma unroll
    for (int vv = 0; vv < 16; vv++){
        int v = vv*2 + vy;
        op[(size_t)v*128 + cx] = tile[cx][v];
    }
}

// wave-per-point trilinear sample from channel-last ct; lane handles 2 channels
__global__ __launch_bounds__(256) void sample_kernel(const float* __restrict__ pcl_mem,
                                                     const float* __restrict__ ct,
                                                     float* __restrict__ feats){
    const int tid  = threadIdx.x;
    const int lane = tid & 63;
    const int p    = blockIdx.x*4 + (tid >> 6);
    const int b    = p >> 16;

    float v0 = pcl_mem[3*p+0], v1 = pcl_mem[3*p+1], v2 = pcl_mem[3*p+2];
    auto src = [](float v){
        float g = 2.0f*v/63.0f - 1.0f;
        g = fminf(fmaxf(g, -2.0f), 2.0f);
        float t = (g + 1.0f)*0.5f*63.0f;
        return fminf(fmaxf(t, 0.0f), 63.0f);
    };
    float ix = src(v0), iy = src(v1), iz = src(v2);
    float fx = floorf(ix), fy = floorf(iy), fz = floorf(iz);
    float wx = ix-fx, wy = iy-fy, wz = iz-fz;
    int x0 = min(max((int)fx,0),63); int x1 = min(x0+1,63);
    int y0 = min(max((int)fy,0),63); int y1 = min(y0+1,63);
    int z0 = min(max((int)fz,0),63); int z1 = min(z0+1,63);
    float wx0 = 1.f-wx, wy0 = 1.f-wy, wz0 = 1.f-wz;

    const float2* base = (const float2*)ct + (size_t)b*VOX*64 + lane;
    float ax = 0.f, ay = 0.f;
#define CORNER(zz,yy,xx,wgt) { \
        float2 cv = base[(size_t)(((zz)*64+(yy))*64+(xx))*64]; \
        float w_ = (wgt); \
        ax = fmaf(w_, cv.x, ax); ay = fmaf(w_, cv.y, ay); }
    CORNER(z0,y0,x0, wz0*wy0*wx0);
    CORNER(z0,y0,x1, wz0*wy0*wx );
    CORNER(z0,y1,x0, wz0*wy *wx0);
    CORNER(z0,y1,x1, wz0*wy *wx );
    CORNER(z1,y0,x0, wz *wy0*wx0);
    CORNER(z1,y0,x1, wz *wy0*wx );
    CORNER(z1,y1,x0, wz *wy *wx0);
    CORNER(z1,y1,x1, wz *wy *wx );
#undef CORNER
    ((float2*)(feats + (size_t)p*CDIM))[lane] = make_float2(ax, ay);
}

// fallback (ws too small): thread per (point, channel), original layout
__global__ __launch_bounds__(256) void sample_slow_kernel(const float* __restrict__ pcl_mem,
                                                          const float* __restrict__ cpl,
                                                          float* __restrict__ feats){
    int gid = blockIdx.x*256 + threadIdx.x;   // p*128 + c
    int p = gid >> 7; int c = gid & 127;
    int b = p >> 16;
    float v0 = pcl_mem[3*p+0], v1 = pcl_mem[3*p+1], v2 = pcl_mem[3*p+2];
    auto src = [](float v){
        float g = 2.0f*v/63.0f - 1.0f;
        g = fminf(fmaxf(g, -2.0f), 2.0f);
        float t = (g + 1.0f)*0.5f*63.0f;
        return fminf(fmaxf(t, 0.0f), 63.0f);
    };
    float ix = src(v0), iy = src(v1), iz = src(v2);
    float fx = floorf(ix), fy = floorf(iy), fz = floorf(iz);
    float wx = ix-fx, wy = iy-fy, wz = iz-fz;
    int x0 = min(max((int)fx,0),63); int x1 = min(x0+1,63);
    int y0 = min(max((int)fy,0),63); int y1 = min(y0+1,63);
    int z0 = min(max((int)fz,0),63); int z1 = min(z0+1,63);
    float wx0 = 1.f-wx, wy0 = 1.f-wy, wz0 = 1.f-wz;
    const float* base = cpl + ((size_t)(b*128 + c))*VOX;
    float acc = 0.f;
    acc = fmaf(wz0*wy0*wx0, base[(z0*64+y0)*64+x0], acc);
    acc = fmaf(wz0*wy0*wx , base[(z0*64+y0)*64+x1], acc);
    acc = fmaf(wz0*wy *wx0, base[(z0*64+y1)*64+x0], acc);
    acc = fmaf(wz0*wy *wx , base[(z0*64+y1)*64+x1], acc);
    acc = fmaf(wz *wy0*wx0, base[(z1*64+y0)*64+x0], acc);
    acc = fmaf(wz *wy0*wx , base[(z1*64+y0)*64+x1], acc);
    acc = fmaf(wz *wy *wx0, base[(z1*64+y1)*64+x0], acc);
    acc = fmaf(wz *wy *wx , base[(z1*64+y1)*64+x1], acc);
    feats[gid] = acc;
}

// ---------------------------------------------------------------------------
// Fused MLP + hypernetwork, WAVE-LEVEL 2x column split.
//   block = 256 threads = 4 waves = 128 points; grid = NPTS/128 = 1024 blocks.
//   wave w: point-group pg = w>>1 (64 points), column-half hf = w&1.
// hf is pinned to an SGPR via readfirstlane so ALL weight/bias addresses are
// provably wave-uniform -> s_load into SGPRs (round-0's scalar path: weights
// cost 0 VGPRs and feed FMA as the scalar operand). Round 2 broke this with
// an intra-wave split (VGPR 88->152, occupancy 24->12%).
// Arithmetic identical to round 2 (passed, absmax 2^-10): same per-element
// FMA orders; only the thread->(point,half) mapping changed.
// ---------------------------------------------------------------------------
__global__ __launch_bounds__(256) void mlp_kernel(
        const float* __restrict__ pcl_mem,
        const float* __restrict__ Wh1, const float* __restrict__ bh1,
        const float* __restrict__ Wh2, const float* __restrict__ bh2,
        const float* __restrict__ bh3,
        const float* __restrict__ feats,
        float* __restrict__ outp)
{
    __shared__ float xbuf[32][128];     // 16 KB: h1a -> h2a -> a1 -> o3 partials
    const int tid  = threadIdx.x;
    const int lane = tid & 63;
    const int wv   = __builtin_amdgcn_readfirstlane(tid >> 6);  // 0..3, SGPR
    const int hf   = wv & 1;            // column half (wave-uniform, SGPR)
    const int pg   = wv >> 1;           // point group (wave-uniform, SGPR)
    const int pl   = pg*64 + lane;      // point within block, 0..127
    const int p    = blockIdx.x*128 + pl;
    const int jq   = hf*4;              // float4-group base of my half (SGPR)

    float xv0, xv1, xv2;
    {
        float v0 = pcl_mem[3*p+0], v1 = pcl_mem[3*p+1], v2 = pcl_mem[3*p+2];
        xv0 = v0 - truncf(v0) - 0.5f;
        xv1 = v1 - truncf(v1) - 0.5f;
        xv2 = v2 - truncf(v2) - 0.5f;
    }

    const float4* f4  = (const float4*)(feats + (size_t)p*CDIM);
    const float4* W1q = (const float4*)Wh1;
    const float4* W2q = (const float4*)Wh2;
    const float4* W3q = (const float4*)g_Wh3p;
    const float4* b1q = (const float4*)bh1;
    const float4* b2q = (const float4*)bh2;
    const float4* b3q = (const float4*)bh3;
    const int RS = WSTRIDE/4;   // 308 float4 per Wh3p row

    // ---- h1 half: 16 cols of leaky(feats @ Wh1 + bh1) ----
    float hh[16];
    #pragma unroll
    for (int q=0;q<4;q++){ float4 bv=b1q[jq+q]; hh[4*q]=bv.x; hh[4*q+1]=bv.y; hh[4*q+2]=bv.z; hh[4*q+3]=bv.w; }
    for (int c4=0;c4<32;c4++){
        float4 f = f4[c4];
        float fs[4] = {f.x, f.y, f.z, f.w};
        #pragma unroll
        for (int cc=0;cc<4;cc++){
            #pragma unroll
            for (int q=0;q<4;q++){
                float4 w = W1q[(c4*4+cc)*8 + jq + q];
                hh[4*q+0] = fmaf(fs[cc], w.x, hh[4*q+0]);
                hh[4*q+1] = fmaf(fs[cc], w.y, hh[4*q+1]);
                hh[4*q+2] = fmaf(fs[cc], w.z, hh[4*q+2]);
                hh[4*q+3] = fmaf(fs[cc], w.w, hh[4*q+3]);
            }
        }
    }
    #pragma unroll
    for (int r=0;r<16;r++){ float a=hh[r]; xbuf[hf*16+r][pl] = fmaxf(a, 0.01f*a); }
    __syncthreads();

    // ---- h2 half: 16 cols of h1a @ Wh2 + bh2 ----
    float h2[16];
    #pragma unroll
    for (int q=0;q<4;q++){ float4 bv=b2q[jq+q]; h2[4*q]=bv.x; h2[4*q+1]=bv.y; h2[4*q+2]=bv.z; h2[4*q+3]=bv.w; }
    #pragma unroll
    for (int i=0;i<32;i++){
        float ai = xbuf[i][pl];
        #pragma unroll
        for (int q=0;q<4;q++){
            float4 w = W2q[i*8 + jq + q];
            h2[4*q+0] = fmaf(ai, w.x, h2[4*q+0]);
            h2[4*q+1] = fmaf(ai, w.y, h2[4*q+1]);
            h2[4*q+2] = fmaf(ai, w.z, h2[4*q+2]);
            h2[4*q+3] = fmaf(ai, w.w, h2[4*q+3]);
        }
    }
    __syncthreads();   // all h1a reads done -> safe to overwrite
    #pragma unroll
    for (int r=0;r<16;r++){ float a=h2[r]; xbuf[hf*16+r][pl] = fmaxf(a, 0.01f*a); }
    __syncthreads();
    float h2a[32];     // full h2a in registers (static-indexed everywhere below)
    #pragma unroll
    for (int k=0;k<32;k++) h2a[k] = xbuf[k][pl];

    // ---- o1 half: 16 cols of x . W1' + b1' (hw cols 0..127), k unrolled ----
    float acc[16];
    #pragma unroll
    for (int q=0;q<4;q++){
        float4 ba=b3q[jq+q], bb=b3q[8+jq+q], bc=b3q[16+jq+q], bd=b3q[24+jq+q];
        acc[4*q+0] = fmaf(xv0,ba.x, fmaf(xv1,bb.x, fmaf(xv2,bc.x, bd.x)));
        acc[4*q+1] = fmaf(xv0,ba.y, fmaf(xv1,bb.y, fmaf(xv2,bc.y, bd.y)));
        acc[4*q+2] = fmaf(xv0,ba.z, fmaf(xv1,bb.z, fmaf(xv2,bc.z, bd.z)));
        acc[4*q+3] = fmaf(xv0,ba.w, fmaf(xv1,bb.w, fmaf(xv2,bc.w, bd.w)));
    }
    #pragma unroll
    for (int k=0;k<32;k++){
        const float4* row = W3q + (size_t)k*RS;
        float hk = h2a[k];
        #pragma unroll
        for (int q=0;q<4;q++){
            float4 wa=row[jq+q], wb=row[8+jq+q], wc=row[16+jq+q], wd=row[24+jq+q];
            acc[4*q+0] = fmaf(hk, fmaf(xv0,wa.x, fmaf(xv1,wb.x, fmaf(xv2,wc.x, wd.x))), acc[4*q+0]);
            acc[4*q+1] = fmaf(hk, fmaf(xv0,wa.y, fmaf(xv1,wb.y, fmaf(xv2,wc.y, wd.y))), acc[4*q+1]);
            acc[4*q+2] = fmaf(hk, fmaf(xv0,wa.z, fmaf(xv1,wb.z, fmaf(xv2,wc.z, wd.z))), acc[4*q+2]);
            acc[4*q+3] = fmaf(hk, fmaf(xv0,wa.w, fmaf(xv1,wb.w, fmaf(xv2,wc.w, wd.w))), acc[4*q+3]);
        }
    }
    __syncthreads();   // all h2a reads from xbuf done -> safe to overwrite
    #pragma unroll
    for (int r=0;r<16;r++){ float a=acc[r]; xbuf[hf*16+r][pl] = fmaxf(a, 0.01f*a); }  // a1
    __syncthreads();

    // ---- o2 init half: b2' + h2a . W3[:,1152..1183], k unrolled ----
    float o2[16];
    #pragma unroll
    for (int q=0;q<4;q++){ float4 bv=b3q[288+jq+q]; o2[4*q]=bv.x; o2[4*q+1]=bv.y; o2[4*q+2]=bv.z; o2[4*q+3]=bv.w; }
    #pragma unroll
    for (int k=0;k<32;k++){
        const float4* row = W3q + (size_t)k*RS + 288;
        float hk = h2a[k];
        #pragma unroll
        for (int q=0;q<4;q++){
            float4 w = row[jq+q];
            o2[4*q+0] = fmaf(hk, w.x, o2[4*q+0]);
            o2[4*q+1] = fmaf(hk, w.y, o2[4*q+1]);
            o2[4*q+2] = fmaf(hk, w.z, o2[4*q+2]);
            o2[4*q+3] = fmaf(hk, w.w, o2[4*q+3]);
        }
    }

    // ---- main contraction: o2[j] += sum_i a1[i] * (bh3 + h2.Wh3)[128+i*32+j] ----
    #pragma unroll 1
    for (int i=0;i<32;i++){
        float ai = xbuf[i][pl];
        float w2[16];
        #pragma unroll
        for (int q=0;q<4;q++){ float4 bv=b3q[32+i*8+jq+q]; w2[4*q]=bv.x; w2[4*q+1]=bv.y; w2[4*q+2]=bv.z; w2[4*q+3]=bv.w; }
        #pragma unroll
        for (int k=0;k<32;k++){
            const float4* row = W3q + (size_t)k*RS + 32 + i*8;
            float hk = h2a[k];
            #pragma unroll
            for (int q=0;q<4;q++){
                float4 w = row[jq+q];
                w2[4*q+0] = fmaf(hk, w.x, w2[4*q+0]);
                w2[4*q+1] = fmaf(hk, w.y, w2[4*q+1]);
                w2[4*q+2] = fmaf(hk, w.z, w2[4*q+2]);
                w2[4*q+3] = fmaf(hk, w.w, w2[4*q+3]);
            }
        }
        #pragma unroll
        for (int r=0;r<16;r++) o2[r] = fmaf(ai, w2[r], o2[r]);
    }

    // ---- final half: w3' cols (hw 1184..1215), partial o3 over my 16 cols ----
    float w3c[16];
    #pragma unroll
    for (int q=0;q<4;q++){ float4 bv=b3q[296+jq+q]; w3c[4*q]=bv.x; w3c[4*q+1]=bv.y; w3c[4*q+2]=bv.z; w3c[4*q+3]=bv.w; }
    #pragma unroll
    for (int k=0;k<32;k++){
        const float4* row = W3q + (size_t)k*RS + 296;
        float hk = h2a[k];
        #pragma unroll
        for (int q=0;q<4;q++){
            float4 w = row[jq+q];
            w3c[4*q+0] = fmaf(hk, w.x, w3c[4*q+0]);
            w3c[4*q+1] = fmaf(hk, w.y, w3c[4*q+1]);
            w3c[4*q+2] = fmaf(hk, w.z, w3c[4*q+2]);
            w3c[4*q+3] = fmaf(hk, w.w, w3c[4*q+3]);
        }
    }
    float part = 0.f;
    #pragma unroll
    for (int r=0;r<16;r++){ float a=o2[r]; a = fmaxf(a, 0.01f*a); part = fmaf(a, w3c[r], part); }

    __syncthreads();   // all a1 reads done -> xbuf reusable for reduction
    xbuf[hf][pl] = part;
    __syncthreads();
    if (hf == 0){   // wave-uniform branch (waves 0 and 2)
        float base = bh3[1216];
        #pragma unroll
        for (int k=0;k<32;k++) base = fmaf(h2a[k], g_Wh3p[k*WSTRIDE + 1216], base);
        outp[p] = base + xbuf[0][pl] + xbuf[1][pl];
    }
}

extern "C" void kernel_launch(void* const* d_in, const int* in_sizes, int n_in,
                              void* d_out, int out_size, void* d_ws, size_t ws_size,
                              hipStream_t stream)
{
    const float* pcl_mem = (const float*)d_in[1];
    const float* c_plane = (const float*)d_in[2];
    const float* Wh1     = (const float*)d_in[3];
    const float* bh1     = (const float*)d_in[4];
    const float* Wh2     = (const float*)d_in[5];
    const float* bh2     = (const float*)d_in[6];
    const float* Wh3     = (const float*)d_in[7];
    const float* bh3     = (const float*)d_in[8];
    float* outp  = (float*)d_out;
    float* feats = outp + NPTS;

    pad_wh3_kernel<<<(32*WCOLS+255)/256, 256, 0, stream>>>(Wh3);

    const size_t ct_bytes = (size_t)NB*VOX*CDIM*sizeof(float);   // 256 MiB
    if (ws_size >= ct_bytes) {
        float* ct = (float*)d_ws;
        transpose_kernel<<<NB*(VOX/32), 256, 0, stream>>>(c_plane, ct);
        sample_kernel<<<NPTS/4, 256, 0, stream>>>(pcl_mem, ct, feats);
    } else {
        sample_slow_kernel<<<(NPTS*CDIM)/256, 256, 0, stream>>>(pcl_mem, c_plane, feats);
    }

    mlp_kernel<<<NPTS/128, 256, 0, stream>>>(pcl_mem, Wh1, bh1, Wh2, bh2, bh3, feats, outp);
}

// Round 4
// 897.527 us; speedup vs baseline: 2.0249x; 1.2679x over previous
//
#include <hip/hip_runtime.h>
#include <cstdint>

#define NB 2
#define NPER 65536
#define NPTS (NB*NPER)
#define CDIM 128
#define SV 64
#define VOX (SV*SV*SV)
#define WCOLS 1217
#define WSTRIDE 1232   // padded row stride (multiple of 16 floats -> 64B-aligned rows)

// Padded Wh3 lives in a static device buffer (rewritten every call; deterministic).
__device__ __align__(16) float g_Wh3p[32*WSTRIDE];

__global__ __launch_bounds__(256) void pad_wh3_kernel(const float* __restrict__ Wh3){
    int idx = blockIdx.x*256 + threadIdx.x;
    if (idx < 32*WCOLS){
        int k = idx / WCOLS;
        int c = idx - k*WCOLS;
        g_Wh3p[k*WSTRIDE + c] = Wh3[idx];
    }
}

// c_plane [B][C=128][VOX] -> ct [B][VOX][C=128]
__global__ __launch_bounds__(256) void transpose_kernel(const float* __restrict__ in,
                                                        float* __restrict__ out){
    __shared__ float tile[128][33];
    const int blk = blockIdx.x;        // NB * (VOX/32) blocks
    const int b  = blk >> 13;          // VOX/32 = 8192
    const int v0 = (blk & 8191) << 5;  // *32
    const int tx = threadIdx.x & 31;
    const int ty = threadIdx.x >> 5;   // 0..7
    const float* ip = in + (size_t)b*128*VOX + v0;
    #pragma unroll
    for (int cc = 0; cc < 16; cc++){
        int c = cc*8 + ty;
        tile[c][tx] = ip[(size_t)c*VOX + tx];
    }
    __syncthreads();
    const int cx = threadIdx.x & 127;
    const int vy = threadIdx.x >> 7;   // 0..1
    float* op = out + ((size_t)b*VOX + v0)*128;
    #pragma unroll
    for (int vv = 0; vv < 16; vv++){
        int v = vv*2 + vy;
        op[(size_t)v*128 + cx] = tile[cx][v];
    }
}

// wave-per-point trilinear sample from channel-last ct; lane handles 2 channels
__global__ __launch_bounds__(256) void sample_kernel(const float* __restrict__ pcl_mem,
                                                     const float* __restrict__ ct,
                                                     float* __restrict__ feats){
    const int tid  = threadIdx.x;
    const int lane = tid & 63;
    const int p    = blockIdx.x*4 + (tid >> 6);
    const int b    = p >> 16;

    float v0 = pcl_mem[3*p+0], v1 = pcl_mem[3*p+1], v2 = pcl_mem[3*p+2];
    auto src = [](float v){
        float g = 2.0f*v/63.0f - 1.0f;
        g = fminf(fmaxf(g, -2.0f), 2.0f);
        float t = (g + 1.0f)*0.5f*63.0f;
        return fminf(fmaxf(t, 0.0f), 63.0f);
    };
    float ix = src(v0), iy = src(v1), iz = src(v2);
    float fx = floorf(ix), fy = floorf(iy), fz = floorf(iz);
    float wx = ix-fx, wy = iy-fy, wz = iz-fz;
    int x0 = min(max((int)fx,0),63); int x1 = min(x0+1,63);
    int y0 = min(max((int)fy,0),63); int y1 = min(y0+1,63);
    int z0 = min(max((int)fz,0),63); int z1 = min(z0+1,63);
    float wx0 = 1.f-wx, wy0 = 1.f-wy, wz0 = 1.f-wz;

    const float2* base = (const float2*)ct + (size_t)b*VOX*64 + lane;
    float ax = 0.f, ay = 0.f;
#define CORNER(zz,yy,xx,wgt) { \
        float2 cv = base[(size_t)(((zz)*64+(yy))*64+(xx))*64]; \
        float w_ = (wgt); \
        ax = fmaf(w_, cv.x, ax); ay = fmaf(w_, cv.y, ay); }
    CORNER(z0,y0,x0, wz0*wy0*wx0);
    CORNER(z0,y0,x1, wz0*wy0*wx );
    CORNER(z0,y1,x0, wz0*wy *wx0);
    CORNER(z0,y1,x1, wz0*wy *wx );
    CORNER(z1,y0,x0, wz *wy0*wx0);
    CORNER(z1,y0,x1, wz *wy0*wx );
    CORNER(z1,y1,x0, wz *wy *wx0);
    CORNER(z1,y1,x1, wz *wy *wx );
#undef CORNER
    ((float2*)(feats + (size_t)p*CDIM))[lane] = make_float2(ax, ay);
}

// fallback (ws too small): thread per (point, channel), original layout
__global__ __launch_bounds__(256) void sample_slow_kernel(const float* __restrict__ pcl_mem,
                                                          const float* __restrict__ cpl,
                                                          float* __restrict__ feats){
    int gid = blockIdx.x*256 + threadIdx.x;   // p*128 + c
    int p = gid >> 7; int c = gid & 127;
    int b = p >> 16;
    float v0 = pcl_mem[3*p+0], v1 = pcl_mem[3*p+1], v2 = pcl_mem[3*p+2];
    auto src = [](float v){
        float g = 2.0f*v/63.0f - 1.0f;
        g = fminf(fmaxf(g, -2.0f), 2.0f);
        float t = (g + 1.0f)*0.5f*63.0f;
        return fminf(fmaxf(t, 0.0f), 63.0f);
    };
    float ix = src(v0), iy = src(v1), iz = src(v2);
    float fx = floorf(ix), fy = floorf(iy), fz = floorf(iz);
    float wx = ix-fx, wy = iy-fy, wz = iz-fz;
    int x0 = min(max((int)fx,0),63); int x1 = min(x0+1,63);
    int y0 = min(max((int)fy,0),63); int y1 = min(y0+1,63);
    int z0 = min(max((int)fz,0),63); int z1 = min(z0+1,63);
    float wx0 = 1.f-wx, wy0 = 1.f-wy, wz0 = 1.f-wz;
    const float* base = cpl + ((size_t)(b*128 + c))*VOX;
    float acc = 0.f;
    acc = fmaf(wz0*wy0*wx0, base[(z0*64+y0)*64+x0], acc);
    acc = fmaf(wz0*wy0*wx , base[(z0*64+y0)*64+x1], acc);
    acc = fmaf(wz0*wy *wx0, base[(z0*64+y1)*64+x0], acc);
    acc = fmaf(wz0*wy *wx , base[(z0*64+y1)*64+x1], acc);
    acc = fmaf(wz *wy0*wx0, base[(z1*64+y0)*64+x0], acc);
    acc = fmaf(wz *wy0*wx , base[(z1*64+y0)*64+x1], acc);
    acc = fmaf(wz *wy *wx0, base[(z1*64+y1)*64+x0], acc);
    acc = fmaf(wz *wy *wx , base[(z1*64+y1)*64+x1], acc);
    feats[gid] = acc;
}

__device__ __forceinline__ void fma4(float (&acc)[32], int jv, float s, float4 w){
    acc[4*jv+0] = fmaf(s, w.x, acc[4*jv+0]);
    acc[4*jv+1] = fmaf(s, w.y, acc[4*jv+1]);
    acc[4*jv+2] = fmaf(s, w.z, acc[4*jv+2]);
    acc[4*jv+3] = fmaf(s, w.w, acc[4*jv+3]);
}

// ---------------------------------------------------------------------------
// Thread-per-point fused MLP + hypernetwork. ONE-WAVE BLOCKS (64 threads):
//   grid = NPTS/64 = 2048 blocks, LDS = 8 KiB/block.
// Residency: VGPR ~88 -> 4 waves/SIMD = 16 waves/CU; LDS 16x8KiB = 128 KiB OK.
// Round 0 was LDS-capped at 2 blocks/CU (64 KiB blocks) = 8 waves/CU; this
// doubles resident waves with IDENTICAL per-thread code (full 32-wide ILP,
// wave-uniform scalar weight loads). Round 2/3 lesson: never split columns
// below wave granularity; round 1 lesson: no min-waves launch bound (spills).
// Arithmetic is bit-identical to the round-0/1 kernels (passed, absmax 2^-10).
// ---------------------------------------------------------------------------
__global__ __launch_bounds__(64) void mlp_kernel(
        const float* __restrict__ pcl_mem,
        const float* __restrict__ Wh1, const float* __restrict__ bh1,
        const float* __restrict__ Wh2, const float* __restrict__ bh2,
        const float* __restrict__ bh3,
        const float* __restrict__ feats,
        float* __restrict__ outp)
{
    __shared__ float lds_a[32][64];    // h1a -> a1 -> leaky(o2); own column only
    const int tid = threadIdx.x;       // 0..63
    const int p   = blockIdx.x*64 + tid;

    float xv0, xv1, xv2;
    {
        float v0 = pcl_mem[3*p+0], v1 = pcl_mem[3*p+1], v2 = pcl_mem[3*p+2];
        xv0 = v0 - truncf(v0) - 0.5f;
        xv1 = v1 - truncf(v1) - 0.5f;
        xv2 = v2 - truncf(v2) - 0.5f;
    }

    const float4* f4  = (const float4*)(feats + (size_t)p*CDIM);
    const float4* W1q = (const float4*)Wh1;
    const float4* W2q = (const float4*)Wh2;
    const float4* W3q = (const float4*)g_Wh3p;
    const float4* b1q = (const float4*)bh1;
    const float4* b2q = (const float4*)bh2;
    const float4* b3q = (const float4*)bh3;
    const int RS = WSTRIDE/4;   // 308 float4 per Wh3p row

    // ---- h1 = leaky(feats @ Wh1 + bh1) ----
    float h1[32];
    #pragma unroll
    for (int jv=0;jv<8;jv++){ float4 bv=b1q[jv]; h1[4*jv]=bv.x; h1[4*jv+1]=bv.y; h1[4*jv+2]=bv.z; h1[4*jv+3]=bv.w; }
    for (int c4=0;c4<32;c4++){
        float4 f = f4[c4];
        float fs[4] = {f.x, f.y, f.z, f.w};
        #pragma unroll
        for (int cc=0;cc<4;cc++){
            #pragma unroll
            for (int jv=0;jv<8;jv++)
                fma4(h1, jv, fs[cc], W1q[(c4*4+cc)*8 + jv]);
        }
    }
    #pragma unroll
    for (int j=0;j<32;j++){ float a=h1[j]; lds_a[j][tid] = fmaxf(a, 0.01f*a); }

    // ---- h2 = leaky(h1a @ Wh2 + bh2) ---- (h2a stays in registers only)
    float h2[32];
    #pragma unroll
    for (int kv=0;kv<8;kv++){ float4 bv=b2q[kv]; h2[4*kv]=bv.x; h2[4*kv+1]=bv.y; h2[4*kv+2]=bv.z; h2[4*kv+3]=bv.w; }
    for (int j=0;j<32;j++){
        float aj = lds_a[j][tid];
        #pragma unroll
        for (int kv=0;kv<8;kv++) fma4(h2, kv, aj, W2q[j*8+kv]);
    }
    float h2a[32];
    #pragma unroll
    for (int k=0;k<32;k++){ float a=h2[k]; h2a[k] = fmaxf(a, 0.01f*a); }

    // ---- o1[j] = x . W1'[:, j] + b1'[j], fused from hw cols 0..127.
    // Chunked: 4 chunks of 8 columns; k unrolled (h2a static). Per-element
    // accumulation order identical to the round-0 full-width version.
    #pragma unroll 1
    for (int jc=0;jc<4;jc++){
        float acc[8];
        #pragma unroll
        for (int q=0;q<2;q++){
            float4 ba=b3q[jc*2+q], bb=b3q[8+jc*2+q], bc=b3q[16+jc*2+q], bd=b3q[24+jc*2+q];
            acc[4*q+0] = fmaf(xv0,ba.x, fmaf(xv1,bb.x, fmaf(xv2,bc.x, bd.x)));
            acc[4*q+1] = fmaf(xv0,ba.y, fmaf(xv1,bb.y, fmaf(xv2,bc.y, bd.y)));
            acc[4*q+2] = fmaf(xv0,ba.z, fmaf(xv1,bb.z, fmaf(xv2,bc.z, bd.z)));
            acc[4*q+3] = fmaf(xv0,ba.w, fmaf(xv1,bb.w, fmaf(xv2,bc.w, bd.w)));
        }
        #pragma unroll
        for (int k=0;k<32;k++){
            const float4* row = W3q + (size_t)k*RS + jc*2;
            float hk = h2a[k];
            #pragma unroll
            for (int q=0;q<2;q++){
                float4 wa=row[q], wb=row[8+q], wc=row[16+q], wd=row[24+q];
                acc[4*q+0] = fmaf(hk, fmaf(xv0,wa.x, fmaf(xv1,wb.x, fmaf(xv2,wc.x, wd.x))), acc[4*q+0]);
                acc[4*q+1] = fmaf(hk, fmaf(xv0,wa.y, fmaf(xv1,wb.y, fmaf(xv2,wc.y, wd.y))), acc[4*q+1]);
                acc[4*q+2] = fmaf(hk, fmaf(xv0,wa.z, fmaf(xv1,wb.z, fmaf(xv2,wc.z, wd.z))), acc[4*q+2]);
                acc[4*q+3] = fmaf(hk, fmaf(xv0,wa.w, fmaf(xv1,wb.w, fmaf(xv2,wc.w, wd.w))), acc[4*q+3]);
            }
        }
        #pragma unroll
        for (int r=0;r<8;r++){ float a=acc[r]; lds_a[jc*8+r][tid] = fmaxf(a, 0.01f*a); }  // a1 chunk
    }

    // ---- o2 init = b2' + h2a . W3[:,1152..1183]  (hw cols 1152..1183), k unrolled ----
    float o2[32];
    #pragma unroll
    for (int jv=0;jv<8;jv++){ float4 bv=b3q[288+jv]; o2[4*jv]=bv.x; o2[4*jv+1]=bv.y; o2[4*jv+2]=bv.z; o2[4*jv+3]=bv.w; }
    #pragma unroll
    for (int k=0;k<32;k++){
        const float4* row = W3q + (size_t)k*RS + 288;
        float hk = h2a[k];
        #pragma unroll
        for (int jv=0;jv<8;jv++) fma4(o2, jv, hk, row[jv]);
    }

    // ---- main contraction: o2[j] += sum_i a1[i] * (bh3 + h2.Wh3)[128+i*32+j] ----
    #pragma unroll 1
    for (int i=0;i<32;i++){
        float ai = lds_a[i][tid];
        float w2[32];
        #pragma unroll
        for (int jv=0;jv<8;jv++){ float4 bv=b3q[32+i*8+jv]; w2[4*jv]=bv.x; w2[4*jv+1]=bv.y; w2[4*jv+2]=bv.z; w2[4*jv+3]=bv.w; }
        #pragma unroll
        for (int k=0;k<32;k++){
            const float4* row = W3q + (size_t)k*RS + 32 + i*8;
            #pragma unroll
            for (int jv=0;jv<8;jv++) fma4(w2, jv, h2a[k], row[jv]);
        }
        #pragma unroll
        for (int j=0;j<32;j++) o2[j] = fmaf(ai, w2[j], o2[j]);
    }

    // stash a2 = leaky(o2) in LDS (a1 is dead) for chunked final read-back
    #pragma unroll
    for (int j=0;j<32;j++){ float a=o2[j]; lds_a[j][tid] = fmaxf(a, 0.01f*a); }

    // ---- final: o3 = a2 . W3' + b3'  (hw cols 1184..1216) ----
    float o3 = bh3[1216];
    #pragma unroll
    for (int k=0;k<32;k++) o3 = fmaf(h2a[k], g_Wh3p[k*WSTRIDE + 1216], o3);
    #pragma unroll 1
    for (int jc=0;jc<4;jc++){
        float w3c[8];
        #pragma unroll
        for (int q=0;q<2;q++){
            float4 bv=b3q[296+jc*2+q];
            w3c[4*q]=bv.x; w3c[4*q+1]=bv.y; w3c[4*q+2]=bv.z; w3c[4*q+3]=bv.w;
        }
        #pragma unroll
        for (int k=0;k<32;k++){
            const float4* row = W3q + (size_t)k*RS + 296 + jc*2;
            float hk = h2a[k];
            #pragma unroll
            for (int q=0;q<2;q++){
                float4 w=row[q];
                w3c[4*q+0] = fmaf(hk, w.x, w3c[4*q+0]);
                w3c[4*q+1] = fmaf(hk, w.y, w3c[4*q+1]);
                w3c[4*q+2] = fmaf(hk, w.z, w3c[4*q+2]);
                w3c[4*q+3] = fmaf(hk, w.w, w3c[4*q+3]);
            }
        }
        #pragma unroll
        for (int r=0;r<8;r++) o3 = fmaf(lds_a[jc*8+r][tid], w3c[r], o3);
    }

    outp[p] = o3;
}

extern "C" void kernel_launch(void* const* d_in, const int* in_sizes, int n_in,
                              void* d_out, int out_size, void* d_ws, size_t ws_size,
                              hipStream_t stream)
{
    const float* pcl_mem = (const float*)d_in[1];
    const float* c_plane = (const float*)d_in[2];
    const float* Wh1     = (const float*)d_in[3];
    const float* bh1     = (const float*)d_in[4];
    const float* Wh2     = (const float*)d_in[5];
    const float* bh2     = (const float*)d_in[6];
    const float* Wh3     = (const float*)d_in[7];
    const float* bh3     = (const float*)d_in[8];
    float* outp  = (float*)d_out;
    float* feats = outp + NPTS;

    pad_wh3_kernel<<<(32*WCOLS+255)/256, 256, 0, stream>>>(Wh3);

    const size_t ct_bytes = (size_t)NB*VOX*CDIM*sizeof(float);   // 256 MiB
    if (ws_size >= ct_bytes) {
        float* ct = (float*)d_ws;
        transpose_kernel<<<NB*(VOX/32), 256, 0, stream>>>(c_plane, ct);
        sample_kernel<<<NPTS/4, 256, 0, stream>>>(pcl_mem, ct, feats);
    } else {
        sample_slow_kernel<<<(NPTS*CDIM)/256, 256, 0, stream>>>(pcl_mem, c_plane, feats);
    }

    mlp_kernel<<<NPTS/64, 64, 0, stream>>>(pcl_mem, Wh1, bh1, Wh2, bh2, bh3, feats, outp);
}